// Round 1
// baseline (866.968 us; speedup 1.0000x reference)
//
#include <hip/hip_runtime.h>

typedef unsigned short u16;
typedef short bf16x8 __attribute__((ext_vector_type(8)));
typedef float f32x4 __attribute__((ext_vector_type(4)));

#define BSZ 8192
#define OUTLD 7168

__device__ __forceinline__ u16 f2bf(float f) {
  union { float f; unsigned u; } v; v.f = f;
  unsigned r = v.u + 0x7FFFu + ((v.u >> 16) & 1u);
  return (u16)(r >> 16);
}
__device__ __forceinline__ float bf2f(u16 h) {
  union { unsigned u; float f; } v; v.u = ((unsigned)h) << 16;
  return v.f;
}
__device__ __forceinline__ float sigmoidf_(float x) { return 1.0f / (1.0f + __expf(-x)); }

// ---- is_first dtype detection (bool8 vs int32 vs f32 0/1) ----
// int32 0/1: OR of words has only bit0.  f32: some word == 0x3F800000 (bytes >1).
// bool8: upper-byte positions set but every byte <= 1.
__global__ void k_detect(const unsigned* __restrict__ isf, int* __restrict__ flag) {
  __shared__ unsigned red;
  if (threadIdx.x == 0) red = 0u;
  __syncthreads();
  unsigned v = 0;
  for (int i = threadIdx.x; i < 2048; i += 256) v |= isf[i];  // first 8KB, safe for all widths
  atomicOr(&red, v);
  __syncthreads();
  if (threadIdx.x == 0)
    *flag = (((red & 0xFFFFFF00u) != 0u) && ((red & 0xFEFEFEFEu) == 0u)) ? 1 : 0;
}

__device__ __forceinline__ bool is_first_row(const void* isf, int fl, int b) {
  return fl ? (((const unsigned char*)isf)[b] != 0) : (((const int*)isf)[b] != 0);
}

// ---- f32 -> bf16 convert, optional per-row is_first zeroing ----
__global__ void k_reset_cvt(const float* __restrict__ src, u16* __restrict__ dst,
                            const void* __restrict__ isf, const int* __restrict__ flag,
                            int c4, long n4, int doReset) {
  int fl = flag ? *flag : 0;
  long stride = (long)gridDim.x * blockDim.x;
  for (long i = blockIdx.x * (long)blockDim.x + threadIdx.x; i < n4; i += stride) {
    float4 v = ((const float4*)src)[i];
    if (doReset && is_first_row(isf, fl, (int)(i / c4))) { v.x = v.y = v.z = v.w = 0.f; }
    ushort4 o; o.x = f2bf(v.x); o.y = f2bf(v.y); o.z = f2bf(v.z); o.w = f2bf(v.w);
    ((ushort4*)dst)[i] = o;
  }
}

// ---- action normalize + tiny K=8 encoder -> x[:, 0:1024] ----
__global__ void k_ae(const float* __restrict__ act, const float* __restrict__ Wact,
                     const float* __restrict__ bact, u16* __restrict__ x) {
  long stride = (long)gridDim.x * blockDim.x;
  for (long t = blockIdx.x * (long)blockDim.x + threadIdx.x; t < (long)BSZ * 1024; t += stride) {
    int b = (int)(t >> 10), h = (int)(t & 1023);
    float4 a0 = ((const float4*)act)[b * 2];
    float4 a1 = ((const float4*)act)[b * 2 + 1];
    float mag = fmaxf(
        fmaxf(fmaxf(fabsf(a0.x), fabsf(a0.y)), fmaxf(fabsf(a0.z), fabsf(a0.w))),
        fmaxf(fmaxf(fabsf(a1.x), fabsf(a1.y)), fmaxf(fabsf(a1.z), fabsf(a1.w))));
    mag = fmaxf(mag, 1.0f);
    float4 w0 = ((const float4*)Wact)[h * 2];
    float4 w1 = ((const float4*)Wact)[h * 2 + 1];
    float dot = a0.x * w0.x + a0.y * w0.y + a0.z * w0.z + a0.w * w0.w
              + a1.x * w1.x + a1.y * w1.y + a1.z * w1.z + a1.w * w1.w;
    x[(long)b * 2048 + h] = f2bf(dot / mag + bact[h]);
  }
}

// ---- generic 128x128 bf16 MFMA GEMM: C = A@W^T (+A2@W2^T) + bias ----
// NT form: A [M,K] row-major, W [N,K] row-major (both K-contiguous).
__global__ __launch_bounds__(256) void gemm128(
    const u16* __restrict__ A1, int lda1, int K1,
    const u16* __restrict__ A2, int lda2, int K2,
    const u16* __restrict__ W1, int ldw1,
    const u16* __restrict__ W2, int ldw2,
    const float* __restrict__ bias,
    float* __restrict__ outF, int ldoF,
    u16* __restrict__ outB, int ldoB,
    int actSilu)
{
  __shared__ __align__(16) u16 lsA[128 * 64];
  __shared__ __align__(16) u16 lsB[128 * 64];
  const int tid = threadIdx.x;
  const int wave = tid >> 6, lane = tid & 63;
  const int m0 = blockIdx.x * 128, n0 = blockIdx.y * 128;
  const int wr = (wave >> 1) * 64, wc = (wave & 1) * 64;
  const int srow = tid >> 3, scol = (tid & 7) * 8;
  const int lrow = lane & 15, lko = (lane >> 4) * 8;

  const f32x4 z4 = {0.f, 0.f, 0.f, 0.f};
  f32x4 acc[4][4];
#pragma unroll
  for (int m = 0; m < 4; ++m)
#pragma unroll
    for (int c = 0; c < 4; ++c) acc[m][c] = z4;

#pragma unroll 1
  for (int phse = 0; phse < 2; ++phse) {
    const u16* A = phse ? A2 : A1;
    const u16* W = phse ? W2 : W1;
    const int lda = phse ? lda2 : lda1;
    const int ldw = phse ? ldw2 : ldw1;
    const int K = phse ? K2 : K1;
#pragma unroll 1
    for (int k0 = 0; k0 < K; k0 += 64) {
      __syncthreads();
#pragma unroll
      for (int i = 0; i < 4; ++i) {
        *(uint4*)&lsA[(i * 32 + srow) * 64 + scol] =
            *(const uint4*)&A[(long)(m0 + i * 32 + srow) * lda + k0 + scol];
        *(uint4*)&lsB[(i * 32 + srow) * 64 + scol] =
            *(const uint4*)&W[(long)(n0 + i * 32 + srow) * ldw + k0 + scol];
      }
      __syncthreads();
#pragma unroll
      for (int kk = 0; kk < 2; ++kk) {
        bf16x8 af[4], wfr[4];
#pragma unroll
        for (int m = 0; m < 4; ++m)
          af[m] = *(const bf16x8*)&lsA[(wr + m * 16 + lrow) * 64 + kk * 32 + lko];
#pragma unroll
        for (int c = 0; c < 4; ++c)
          wfr[c] = *(const bf16x8*)&lsB[(wc + c * 16 + lrow) * 64 + kk * 32 + lko];
#pragma unroll
        for (int m = 0; m < 4; ++m)
#pragma unroll
          for (int c = 0; c < 4; ++c)
            acc[m][c] = __builtin_amdgcn_mfma_f32_16x16x32_bf16(af[m], wfr[c], acc[m][c], 0, 0, 0);
      }
    }
  }

#pragma unroll
  for (int c = 0; c < 4; ++c) {
    const int col = n0 + wc + c * 16 + lrow;
    const float bv = bias ? bias[col] : 0.f;
#pragma unroll
    for (int m = 0; m < 4; ++m) {
      const int rowb = m0 + wr + m * 16 + (lane >> 4) * 4;
#pragma unroll
      for (int r = 0; r < 4; ++r) {
        float v = acc[m][c][r] + bv;
        if (actSilu) v = v * sigmoidf_(v);
        if (outF) outF[(long)(rowb + r) * ldoF + col] = v;
        if (outB) outB[(long)(rowb + r) * ldoB + col] = f2bf(v);
      }
    }
  }
}

// ---- block-diagonal GRU: 3 gates for same 64 cols in one block, fused epilogue ----
__global__ __launch_bounds__(256) void gru128(
    const u16* __restrict__ xbuf, const u16* __restrict__ hbuf,
    const u16* __restrict__ Wih, const u16* __restrict__ Whh,
    const float* __restrict__ bih, const float* __restrict__ bhh,
    float* __restrict__ outF, u16* __restrict__ hnew)
{
  __shared__ __align__(16) u16 lsA[128 * 64];
  __shared__ __align__(16) u16 lsW[3 * 64 * 64];
  const int tid = threadIdx.x;
  const int wave = tid >> 6, lane = tid & 63;
  const int m0 = blockIdx.x * 128;
  const int blk = blockIdx.y >> 3;
  const int s0 = (blockIdx.y & 7) * 64;
  const int srow = tid >> 3, scol = (tid & 7) * 8;
  const int lrow = lane & 15, lko = (lane >> 4) * 8;

  const f32x4 z4 = {0.f, 0.f, 0.f, 0.f};
  f32x4 acc[3][2][4];
#pragma unroll
  for (int g = 0; g < 3; ++g)
#pragma unroll
    for (int m = 0; m < 2; ++m)
#pragma unroll
      for (int c = 0; c < 4; ++c) acc[g][m][c] = z4;

#pragma unroll 1
  for (int phse = 0; phse < 2; ++phse) {
    const u16* A = phse ? (hbuf + blk * 512) : (xbuf + blk * 256);
    const u16* W = phse ? (Whh + (long)blk * 1536 * 512) : (Wih + (long)blk * 1536 * 256);
    const int lda = phse ? 4096 : 2048;
    const int ldw = phse ? 512 : 256;
    const int K = phse ? 512 : 256;
#pragma unroll 1
    for (int k0 = 0; k0 < K; k0 += 64) {
      __syncthreads();
#pragma unroll
      for (int i = 0; i < 4; ++i)
        *(uint4*)&lsA[(i * 32 + srow) * 64 + scol] =
            *(const uint4*)&A[(long)(m0 + i * 32 + srow) * lda + k0 + scol];
#pragma unroll
      for (int g = 0; g < 3; ++g)
#pragma unroll
        for (int i = 0; i < 2; ++i)
          *(uint4*)&lsW[g * 4096 + (i * 32 + srow) * 64 + scol] =
              *(const uint4*)&W[(long)(g * 512 + s0 + i * 32 + srow) * ldw + k0 + scol];
      __syncthreads();
#pragma unroll
      for (int kk = 0; kk < 2; ++kk) {
        bf16x8 af[2], wfr[3][4];
#pragma unroll
        for (int m = 0; m < 2; ++m)
          af[m] = *(const bf16x8*)&lsA[(wave * 32 + m * 16 + lrow) * 64 + kk * 32 + lko];
#pragma unroll
        for (int g = 0; g < 3; ++g)
#pragma unroll
          for (int c = 0; c < 4; ++c)
            wfr[g][c] = *(const bf16x8*)&lsW[g * 4096 + (c * 16 + lrow) * 64 + kk * 32 + lko];
#pragma unroll
        for (int g = 0; g < 3; ++g)
#pragma unroll
          for (int m = 0; m < 2; ++m)
#pragma unroll
            for (int c = 0; c < 4; ++c)
              acc[g][m][c] = __builtin_amdgcn_mfma_f32_16x16x32_bf16(af[m], wfr[g][c], acc[g][m][c], 0, 0, 0);
      }
    }
  }

#pragma unroll
  for (int c = 0; c < 4; ++c) {
    const int s = s0 + c * 16 + lrow;
    const int bb = blk * 1536 + s;
    const float br = bih[bb] + bhh[bb];
    const float bu = bih[bb + 512] + bhh[bb + 512];
    const float bc = bih[bb + 1024] + bhh[bb + 1024];
    const int hcol = blk * 512 + s;
#pragma unroll
    for (int m = 0; m < 2; ++m) {
      const int rowb = m0 + wave * 32 + m * 16 + (lane >> 4) * 4;
#pragma unroll
      for (int r = 0; r < 4; ++r) {
        const int row = rowb + r;
        const float gr = acc[0][m][c][r] + br;
        const float gu = acc[1][m][c][r] + bu;
        const float gc = acc[2][m][c][r] + bc;
        const float rr = sigmoidf_(gr);
        const float uu = sigmoidf_(gu);
        const float cand = tanhf(rr * gc);
        const float h = bf2f(hbuf[(long)row * 4096 + hcol]);
        const float hn = (1.f - uu) * h + uu * cand;
        outF[(long)row * OUTLD + hcol] = hn;
        hnew[(long)row * 4096 + hcol] = f2bf(hn);
      }
    }
  }
}

// ---- softmax over C=32 groups + unimix ----
__global__ void k_softmax(float* __restrict__ out) {
  int t = blockIdx.x * blockDim.x + threadIdx.x;  // b*32+g
  if (t >= BSZ * 32) return;
  int b = t >> 5, g = t & 31;
  const float* src = out + (long)b * OUTLD + 4096 + g * 32;
  float* dst = out + (long)b * OUTLD + 5120 + g * 32;
  float v[32];
#pragma unroll
  for (int i = 0; i < 8; ++i) {
    float4 q = ((const float4*)src)[i];
    v[4 * i] = q.x; v[4 * i + 1] = q.y; v[4 * i + 2] = q.z; v[4 * i + 3] = q.w;
  }
  float m = v[0];
#pragma unroll
  for (int i = 1; i < 32; ++i) m = fmaxf(m, v[i]);
  float ssum = 0.f;
#pragma unroll
  for (int i = 0; i < 32; ++i) { v[i] = __expf(v[i] - m); ssum += v[i]; }
  float inv = 0.99f / ssum;
#pragma unroll
  for (int i = 0; i < 8; ++i) {
    float4 q;
    q.x = v[4 * i] * inv + 3.125e-4f;
    q.y = v[4 * i + 1] * inv + 3.125e-4f;
    q.z = v[4 * i + 2] * inv + 3.125e-4f;
    q.w = v[4 * i + 3] * inv + 3.125e-4f;
    ((float4*)dst)[i] = q;
  }
}

extern "C" void kernel_launch(void* const* d_in, const int* in_sizes, int n_in,
                              void* d_out, int out_size, void* d_ws, size_t ws_size,
                              hipStream_t stream) {
  const float* det   = (const float*)d_in[0];
  const float* stoch = (const float*)d_in[1];
  const float* pact  = (const float*)d_in[2];
  const float* embed = (const float*)d_in[3];
  const void*  isf   = d_in[4];
  const float* Wact  = (const float*)d_in[5];
  const float* bact  = (const float*)d_in[6];
  const float* Wst   = (const float*)d_in[7];
  const float* bst   = (const float*)d_in[8];
  const float* Wih   = (const float*)d_in[9];
  const float* bih   = (const float*)d_in[10];
  const float* Whh   = (const float*)d_in[11];
  const float* bhh   = (const float*)d_in[12];
  const float* Wpr1  = (const float*)d_in[13];
  const float* bpr1  = (const float*)d_in[14];
  const float* Wpr2  = (const float*)d_in[15];
  const float* bpr2  = (const float*)d_in[16];
  const float* Wpo1  = (const float*)d_in[17];
  const float* bpo1  = (const float*)d_in[18];
  const float* Wpo2  = (const float*)d_in[19];
  const float* bpo2  = (const float*)d_in[20];
  float* out = (float*)d_out;

  // ws layout (u16 elements after a 256B header). Total ~235 MB.
  int* flag = (int*)d_ws;
  u16* wsu  = (u16*)((char*)d_ws + 256);
  u16* bWst  = wsu;                   // 1,048,576
  u16* bWih  = wsu + 1048576UL;       // 3,145,728
  u16* bWhh  = wsu + 4194304UL;       // 6,291,456
  u16* bWpr1 = wsu + 10485760UL;      // 4,194,304
  u16* bWpr2 = wsu + 14680064UL;      // 1,048,576
  u16* bWpo1 = wsu + 15728640UL;      // 5,242,880
  u16* bWpo2 = wsu + 20971520UL;      // 1,048,576
  u16* bufX  = wsu + 22020096UL;      // 16,777,216  [B,2048]
  u16* bufSt = wsu + 38797312UL;      // 8,388,608   stoch -> later ph
  u16* bufHb = wsu + 47185920UL;      // 33,554,432  hb -> later qh
  u16* bufHn = wsu + 80740352UL;      // 33,554,432  h_new bf16
  u16* bufEm = wsu + 114294784UL;     // 8,388,608   embed bf16

  k_detect<<<dim3(1), dim3(256), 0, stream>>>((const unsigned*)isf, flag);

  // weight conversions f32 -> bf16
  struct CV { const float* s; u16* d; long n; };
  CV cvs[7] = {
    {Wst,  bWst,  1048576L}, {Wih,  bWih,  3145728L}, {Whh,  bWhh,  6291456L},
    {Wpr1, bWpr1, 4194304L}, {Wpr2, bWpr2, 1048576L}, {Wpo1, bWpo1, 5242880L},
    {Wpo2, bWpo2, 1048576L}
  };
  for (int i = 0; i < 7; ++i) {
    long n4 = cvs[i].n / 4;
    int blocks = (int)((n4 + 255) / 256); if (blocks > 4096) blocks = 4096;
    k_reset_cvt<<<dim3(blocks), dim3(256), 0, stream>>>(
        cvs[i].s, cvs[i].d, (const void*)nullptr, (const int*)nullptr, 1, n4, 0);
  }

  // input prep
  k_ae<<<dim3(4096), dim3(256), 0, stream>>>(pact, Wact, bact, bufX);
  k_reset_cvt<<<dim3(4096), dim3(256), 0, stream>>>(stoch, bufSt, isf, flag, 256, 2097152L, 1);
  k_reset_cvt<<<dim3(4096), dim3(256), 0, stream>>>(det, bufHb, isf, flag, 1024, 8388608L, 1);
  k_reset_cvt<<<dim3(4096), dim3(256), 0, stream>>>(embed, bufEm, (const void*)nullptr,
                                                    (const int*)nullptr, 256, 2097152L, 0);

  // se = stoch @ Wst^T + b  -> x[:, 1024:2048]
  gemm128<<<dim3(64, 8), dim3(256), 0, stream>>>(
      bufSt, 1024, 1024, (const u16*)nullptr, 0, 0,
      bWst, 1024, (const u16*)nullptr, 0,
      bst, (float*)nullptr, 0, bufX + 1024, 2048, 0);

  // GRU -> h_new (f32 to out cols [0,4096), bf16 to ws)
  gru128<<<dim3(64, 64), dim3(256), 0, stream>>>(bufX, bufHb, bWih, bWhh, bih, bhh, out, bufHn);

  // ph = silu(h_new @ Wpr1^T + b) -> reuses stoch buffer
  gemm128<<<dim3(64, 8), dim3(256), 0, stream>>>(
      bufHn, 4096, 4096, (const u16*)nullptr, 0, 0,
      bWpr1, 4096, (const u16*)nullptr, 0,
      bpr1, (float*)nullptr, 0, bufSt, 1024, 1);

  // qh = silu([h_new, embed] @ Wpo1^T + b) -> reuses hb buffer
  gemm128<<<dim3(64, 8), dim3(256), 0, stream>>>(
      bufHn, 4096, 4096, bufEm, 1024, 1024,
      bWpo1, 5120, bWpo1 + 4096, 5120,
      bpo1, (float*)nullptr, 0, bufHb, 1024, 1);

  // prior_logits -> out cols [4096,5120)
  gemm128<<<dim3(64, 8), dim3(256), 0, stream>>>(
      bufSt, 1024, 1024, (const u16*)nullptr, 0, 0,
      bWpr2, 1024, (const u16*)nullptr, 0,
      bpr2, out + 4096, OUTLD, (u16*)nullptr, 0, 0);

  // post_logits -> out cols [6144,7168)
  gemm128<<<dim3(64, 8), dim3(256), 0, stream>>>(
      bufHb, 1024, 1024, (const u16*)nullptr, 0, 0,
      bWpo2, 1024, (const u16*)nullptr, 0,
      bpo2, out + 6144, OUTLD, (u16*)nullptr, 0, 0);

  // softmax + unimix -> out cols [5120,6144)
  k_softmax<<<dim3(1024), dim3(256), 0, stream>>>(out);
}

// Round 2
// 847.228 us; speedup vs baseline: 1.0233x; 1.0233x over previous
//
#include <hip/hip_runtime.h>

typedef unsigned short u16;
typedef short bf16x8 __attribute__((ext_vector_type(8)));
typedef float f32x4 __attribute__((ext_vector_type(4)));

#define BSZ 8192
#define OUTLD 7168

__device__ __forceinline__ u16 f2bf(float f) {
  union { float f; unsigned u; } v; v.f = f;
  unsigned r = v.u + 0x7FFFu + ((v.u >> 16) & 1u);
  return (u16)(r >> 16);
}
__device__ __forceinline__ float bf2f(u16 h) {
  union { unsigned u; float f; } v; v.u = ((unsigned)h) << 16;
  return v.f;
}
__device__ __forceinline__ float sigmoidf_(float x) { return 1.0f / (1.0f + __expf(-x)); }

// async global->LDS, 16B per lane; lds dest = wave-uniform base + lane*16
__device__ __forceinline__ void gload16(const u16* g, u16* l) {
  __builtin_amdgcn_global_load_lds(
      (const __attribute__((address_space(1))) void*)g,
      (__attribute__((address_space(3))) void*)l, 16, 0, 0);
}

// ---- is_first dtype detection (bool8 vs int32 vs f32 0/1) ----
__global__ void k_detect(const unsigned* __restrict__ isf, int* __restrict__ flag) {
  __shared__ unsigned red;
  if (threadIdx.x == 0) red = 0u;
  __syncthreads();
  unsigned v = 0;
  for (int i = threadIdx.x; i < 2048; i += 256) v |= isf[i];
  atomicOr(&red, v);
  __syncthreads();
  if (threadIdx.x == 0)
    *flag = (((red & 0xFFFFFF00u) != 0u) && ((red & 0xFEFEFEFEu) == 0u)) ? 1 : 0;
}

__device__ __forceinline__ bool is_first_row(const void* isf, int fl, int b) {
  return fl ? (((const unsigned char*)isf)[b] != 0) : (((const int*)isf)[b] != 0);
}

// ---- f32 -> bf16 convert, optional per-row is_first zeroing ----
__global__ void k_reset_cvt(const float* __restrict__ src, u16* __restrict__ dst,
                            const void* __restrict__ isf, const int* __restrict__ flag,
                            int c4, long n4, int doReset) {
  int fl = flag ? *flag : 0;
  long stride = (long)gridDim.x * blockDim.x;
  for (long i = blockIdx.x * (long)blockDim.x + threadIdx.x; i < n4; i += stride) {
    float4 v = ((const float4*)src)[i];
    if (doReset && is_first_row(isf, fl, (int)(i / c4))) { v.x = v.y = v.z = v.w = 0.f; }
    ushort4 o; o.x = f2bf(v.x); o.y = f2bf(v.y); o.z = f2bf(v.z); o.w = f2bf(v.w);
    ((ushort4*)dst)[i] = o;
  }
}

// ---- action normalize + tiny K=8 encoder -> x[:, 0:1024] (4 h per thread) ----
__global__ void k_ae(const float* __restrict__ act, const float* __restrict__ Wact,
                     const float* __restrict__ bact, u16* __restrict__ x) {
  long stride = (long)gridDim.x * blockDim.x;
  for (long t = blockIdx.x * (long)blockDim.x + threadIdx.x; t < (long)BSZ * 256; t += stride) {
    int b = (int)(t >> 8), h0 = (int)(t & 255) * 4;
    float4 a0 = ((const float4*)act)[b * 2];
    float4 a1 = ((const float4*)act)[b * 2 + 1];
    float mag = fmaxf(
        fmaxf(fmaxf(fabsf(a0.x), fabsf(a0.y)), fmaxf(fabsf(a0.z), fabsf(a0.w))),
        fmaxf(fmaxf(fabsf(a1.x), fabsf(a1.y)), fmaxf(fabsf(a1.z), fabsf(a1.w))));
    float inv = 1.0f / fmaxf(mag, 1.0f);
    ushort4 o;
    u16* op = (u16*)&o;
#pragma unroll
    for (int j = 0; j < 4; ++j) {
      int h = h0 + j;
      float4 w0 = ((const float4*)Wact)[h * 2];
      float4 w1 = ((const float4*)Wact)[h * 2 + 1];
      float dot = a0.x * w0.x + a0.y * w0.y + a0.z * w0.z + a0.w * w0.w
                + a1.x * w1.x + a1.y * w1.y + a1.z * w1.z + a1.w * w1.w;
      op[j] = f2bf(dot * inv + bact[h]);
    }
    *(ushort4*)&x[(long)b * 2048 + h0] = o;
  }
}

// ---- generic 128x128 bf16 MFMA GEMM: C = A@W^T (+A2@W2^T) + bias ----
// NT form: A [M,K] row-major, W [N,K] row-major (both K-contiguous).
// Staging: global_load_lds width-16, linear LDS [128][64].
__global__ __launch_bounds__(256) void gemm128(
    const u16* __restrict__ A1, int lda1, int K1,
    const u16* __restrict__ A2, int lda2, int K2,
    const u16* __restrict__ W1, int ldw1,
    const u16* __restrict__ W2, int ldw2,
    const float* __restrict__ bias,
    float* __restrict__ outF, int ldoF,
    u16* __restrict__ outB, int ldoB,
    int actSilu)
{
  __shared__ __align__(16) u16 lsA[128 * 64];
  __shared__ __align__(16) u16 lsB[128 * 64];
  const int tid = threadIdx.x;
  const int wave = tid >> 6, lane = tid & 63;
  const int m0 = blockIdx.x * 128, n0 = blockIdx.y * 128;
  const int wr = (wave >> 1) * 64, wc = (wave & 1) * 64;
  const int lrow = lane & 15, lko = (lane >> 4) * 8;
  // staging geometry: per call, this lane's element = row (wave*8 + lane/8), col (lane&7)*8
  const int grow = wave * 8 + (lane >> 3);
  const int gcol = (lane & 7) * 8;

  const f32x4 z4 = {0.f, 0.f, 0.f, 0.f};
  f32x4 acc[4][4];
#pragma unroll
  for (int m = 0; m < 4; ++m)
#pragma unroll
    for (int c = 0; c < 4; ++c) acc[m][c] = z4;

#pragma unroll 1
  for (int phse = 0; phse < 2; ++phse) {
    const u16* A = phse ? A2 : A1;
    const u16* W = phse ? W2 : W1;
    const int lda = phse ? lda2 : lda1;
    const int ldw = phse ? ldw2 : ldw1;
    const int K = phse ? K2 : K1;
#pragma unroll 1
    for (int k0 = 0; k0 < K; k0 += 64) {
      __syncthreads();
#pragma unroll
      for (int i = 0; i < 4; ++i) {
        gload16(&A[(long)(m0 + i * 32 + grow) * lda + k0 + gcol], &lsA[i * 2048 + wave * 512]);
        gload16(&W[(long)(n0 + i * 32 + grow) * ldw + k0 + gcol], &lsB[i * 2048 + wave * 512]);
      }
      __syncthreads();
#pragma unroll
      for (int kk = 0; kk < 2; ++kk) {
        bf16x8 af[4], wfr[4];
#pragma unroll
        for (int m = 0; m < 4; ++m)
          af[m] = *(const bf16x8*)&lsA[(wr + m * 16 + lrow) * 64 + kk * 32 + lko];
#pragma unroll
        for (int c = 0; c < 4; ++c)
          wfr[c] = *(const bf16x8*)&lsB[(wc + c * 16 + lrow) * 64 + kk * 32 + lko];
#pragma unroll
        for (int m = 0; m < 4; ++m)
#pragma unroll
          for (int c = 0; c < 4; ++c)
            acc[m][c] = __builtin_amdgcn_mfma_f32_16x16x32_bf16(af[m], wfr[c], acc[m][c], 0, 0, 0);
      }
    }
  }

#pragma unroll
  for (int c = 0; c < 4; ++c) {
    const int col = n0 + wc + c * 16 + lrow;
    const float bv = bias ? bias[col] : 0.f;
#pragma unroll
    for (int m = 0; m < 4; ++m) {
      const int rowb = m0 + wr + m * 16 + (lane >> 4) * 4;
#pragma unroll
      for (int r = 0; r < 4; ++r) {
        float v = acc[m][c][r] + bv;
        if (actSilu) v = v * sigmoidf_(v);
        if (outF) outF[(long)(rowb + r) * ldoF + col] = v;
        if (outB) outB[(long)(rowb + r) * ldoB + col] = f2bf(v);
      }
    }
  }
}

// ---- block-diagonal GRU: 3 gates for same 64 cols in one block, fused epilogue ----
__global__ __launch_bounds__(256) void gru128(
    const u16* __restrict__ xbuf, const u16* __restrict__ hbuf,
    const u16* __restrict__ Wih, const u16* __restrict__ Whh,
    const float* __restrict__ bih, const float* __restrict__ bhh,
    float* __restrict__ outF, u16* __restrict__ hnew)
{
  __shared__ __align__(16) u16 lsA[128 * 64];
  __shared__ __align__(16) u16 lsW[3 * 64 * 64];
  const int tid = threadIdx.x;
  const int wave = tid >> 6, lane = tid & 63;
  const int m0 = blockIdx.x * 128;
  const int blk = blockIdx.y >> 3;
  const int s0 = (blockIdx.y & 7) * 64;
  const int lrow = lane & 15, lko = (lane >> 4) * 8;
  const int grow = wave * 8 + (lane >> 3);   // A staging row within 32-row chunk
  const int gcol = (lane & 7) * 8;

  const f32x4 z4 = {0.f, 0.f, 0.f, 0.f};
  f32x4 acc[3][2][4];
#pragma unroll
  for (int g = 0; g < 3; ++g)
#pragma unroll
    for (int m = 0; m < 2; ++m)
#pragma unroll
      for (int c = 0; c < 4; ++c) acc[g][m][c] = z4;

#pragma unroll 1
  for (int phse = 0; phse < 2; ++phse) {
    const u16* A = phse ? (hbuf + blk * 512) : (xbuf + blk * 256);
    const u16* W = phse ? (Whh + (long)blk * 1536 * 512) : (Wih + (long)blk * 1536 * 256);
    const int lda = phse ? 4096 : 2048;
    const int ldw = phse ? 512 : 256;
    const int K = phse ? 512 : 256;
#pragma unroll 1
    for (int k0 = 0; k0 < K; k0 += 64) {
      __syncthreads();
#pragma unroll
      for (int i = 0; i < 4; ++i)
        gload16(&A[(long)(m0 + i * 32 + grow) * lda + k0 + gcol], &lsA[i * 2048 + wave * 512]);
      // W tile: 3 gates x 64 rows x 64 cols = 12288 u16 = 24 chunks of 512
#pragma unroll
      for (int j = 0; j < 6; ++j) {
        const int idx = j * 4 + wave;           // chunk 0..23
        const int off = idx * 512;
        const int g = off >> 12;                // gate
        const int r0 = (off & 4095) >> 6;       // starting row within gate tile
        gload16(&W[(long)(g * 512 + s0 + r0 + (lane >> 3)) * ldw + k0 + gcol], &lsW[off]);
      }
      __syncthreads();
#pragma unroll
      for (int kk = 0; kk < 2; ++kk) {
        bf16x8 af[2], wfr[3][4];
#pragma unroll
        for (int m = 0; m < 2; ++m)
          af[m] = *(const bf16x8*)&lsA[(wave * 32 + m * 16 + lrow) * 64 + kk * 32 + lko];
#pragma unroll
        for (int g = 0; g < 3; ++g)
#pragma unroll
          for (int c = 0; c < 4; ++c)
            wfr[g][c] = *(const bf16x8*)&lsW[g * 4096 + (c * 16 + lrow) * 64 + kk * 32 + lko];
#pragma unroll
        for (int g = 0; g < 3; ++g)
#pragma unroll
          for (int m = 0; m < 2; ++m)
#pragma unroll
            for (int c = 0; c < 4; ++c)
              acc[g][m][c] = __builtin_amdgcn_mfma_f32_16x16x32_bf16(af[m], wfr[g][c], acc[g][m][c], 0, 0, 0);
      }
    }
  }

#pragma unroll
  for (int c = 0; c < 4; ++c) {
    const int s = s0 + c * 16 + lrow;
    const int bb = blk * 1536 + s;
    const float br = bih[bb] + bhh[bb];
    const float bu = bih[bb + 512] + bhh[bb + 512];
    const float bc = bih[bb + 1024] + bhh[bb + 1024];
    const int hcol = blk * 512 + s;
#pragma unroll
    for (int m = 0; m < 2; ++m) {
      const int rowb = m0 + wave * 32 + m * 16 + (lane >> 4) * 4;
#pragma unroll
      for (int r = 0; r < 4; ++r) {
        const int row = rowb + r;
        const float gr = acc[0][m][c][r] + br;
        const float gu = acc[1][m][c][r] + bu;
        const float gc = acc[2][m][c][r] + bc;
        const float rr = sigmoidf_(gr);
        const float uu = sigmoidf_(gu);
        const float cand = tanhf(rr * gc);
        const float h = bf2f(hbuf[(long)row * 4096 + hcol]);
        const float hn = (1.f - uu) * h + uu * cand;
        outF[(long)row * OUTLD + hcol] = hn;
        hnew[(long)row * 4096 + hcol] = f2bf(hn);
      }
    }
  }
}

// ---- softmax over C=32 groups + unimix ----
__global__ void k_softmax(float* __restrict__ out) {
  int t = blockIdx.x * blockDim.x + threadIdx.x;  // b*32+g
  if (t >= BSZ * 32) return;
  int b = t >> 5, g = t & 31;
  const float* src = out + (long)b * OUTLD + 4096 + g * 32;
  float* dst = out + (long)b * OUTLD + 5120 + g * 32;
  float v[32];
#pragma unroll
  for (int i = 0; i < 8; ++i) {
    float4 q = ((const float4*)src)[i];
    v[4 * i] = q.x; v[4 * i + 1] = q.y; v[4 * i + 2] = q.z; v[4 * i + 3] = q.w;
  }
  float m = v[0];
#pragma unroll
  for (int i = 1; i < 32; ++i) m = fmaxf(m, v[i]);
  float ssum = 0.f;
#pragma unroll
  for (int i = 0; i < 32; ++i) { v[i] = __expf(v[i] - m); ssum += v[i]; }
  float inv = 0.99f / ssum;
#pragma unroll
  for (int i = 0; i < 8; ++i) {
    float4 q;
    q.x = v[4 * i] * inv + 3.125e-4f;
    q.y = v[4 * i + 1] * inv + 3.125e-4f;
    q.z = v[4 * i + 2] * inv + 3.125e-4f;
    q.w = v[4 * i + 3] * inv + 3.125e-4f;
    ((float4*)dst)[i] = q;
  }
}

extern "C" void kernel_launch(void* const* d_in, const int* in_sizes, int n_in,
                              void* d_out, int out_size, void* d_ws, size_t ws_size,
                              hipStream_t stream) {
  const float* det   = (const float*)d_in[0];
  const float* stoch = (const float*)d_in[1];
  const float* pact  = (const float*)d_in[2];
  const float* embed = (const float*)d_in[3];
  const void*  isf   = d_in[4];
  const float* Wact  = (const float*)d_in[5];
  const float* bact  = (const float*)d_in[6];
  const float* Wst   = (const float*)d_in[7];
  const float* bst   = (const float*)d_in[8];
  const float* Wih   = (const float*)d_in[9];
  const float* bih   = (const float*)d_in[10];
  const float* Whh   = (const float*)d_in[11];
  const float* bhh   = (const float*)d_in[12];
  const float* Wpr1  = (const float*)d_in[13];
  const float* bpr1  = (const float*)d_in[14];
  const float* Wpr2  = (const float*)d_in[15];
  const float* bpr2  = (const float*)d_in[16];
  const float* Wpo1  = (const float*)d_in[17];
  const float* bpo1  = (const float*)d_in[18];
  const float* Wpo2  = (const float*)d_in[19];
  const float* bpo2  = (const float*)d_in[20];
  float* out = (float*)d_out;

  // ws layout (u16 elements after a 256B header). Total ~235 MB.
  int* flag = (int*)d_ws;
  u16* wsu  = (u16*)((char*)d_ws + 256);
  u16* bWst  = wsu;                   // 1,048,576
  u16* bWih  = wsu + 1048576UL;       // 3,145,728
  u16* bWhh  = wsu + 4194304UL;       // 6,291,456
  u16* bWpr1 = wsu + 10485760UL;      // 4,194,304
  u16* bWpr2 = wsu + 14680064UL;      // 1,048,576
  u16* bWpo1 = wsu + 15728640UL;      // 5,242,880
  u16* bWpo2 = wsu + 20971520UL;      // 1,048,576
  u16* bufX  = wsu + 22020096UL;      // 16,777,216  [B,2048]
  u16* bufSt = wsu + 38797312UL;      // 8,388,608   stoch -> later ph
  u16* bufHb = wsu + 47185920UL;      // 33,554,432  hb -> later qh
  u16* bufHn = wsu + 80740352UL;      // 33,554,432  h_new bf16
  u16* bufEm = wsu + 114294784UL;     // 8,388,608   embed bf16

  k_detect<<<dim3(1), dim3(256), 0, stream>>>((const unsigned*)isf, flag);

  // weight conversions f32 -> bf16
  struct CV { const float* s; u16* d; long n; };
  CV cvs[7] = {
    {Wst,  bWst,  1048576L}, {Wih,  bWih,  3145728L}, {Whh,  bWhh,  6291456L},
    {Wpr1, bWpr1, 4194304L}, {Wpr2, bWpr2, 1048576L}, {Wpo1, bWpo1, 5242880L},
    {Wpo2, bWpo2, 1048576L}
  };
  for (int i = 0; i < 7; ++i) {
    long n4 = cvs[i].n / 4;
    int blocks = (int)((n4 + 255) / 256); if (blocks > 4096) blocks = 4096;
    k_reset_cvt<<<dim3(blocks), dim3(256), 0, stream>>>(
        cvs[i].s, cvs[i].d, (const void*)nullptr, (const int*)nullptr, 1, n4, 0);
  }

  // input prep
  k_ae<<<dim3(2048), dim3(256), 0, stream>>>(pact, Wact, bact, bufX);
  k_reset_cvt<<<dim3(4096), dim3(256), 0, stream>>>(stoch, bufSt, isf, flag, 256, 2097152L, 1);
  k_reset_cvt<<<dim3(4096), dim3(256), 0, stream>>>(det, bufHb, isf, flag, 1024, 8388608L, 1);
  k_reset_cvt<<<dim3(4096), dim3(256), 0, stream>>>(embed, bufEm, (const void*)nullptr,
                                                    (const int*)nullptr, 256, 2097152L, 0);

  // se = stoch @ Wst^T + b  -> x[:, 1024:2048]
  gemm128<<<dim3(64, 8), dim3(256), 0, stream>>>(
      bufSt, 1024, 1024, (const u16*)nullptr, 0, 0,
      bWst, 1024, (const u16*)nullptr, 0,
      bst, (float*)nullptr, 0, bufX + 1024, 2048, 0);

  // GRU -> h_new (f32 to out cols [0,4096), bf16 to ws)
  gru128<<<dim3(64, 64), dim3(256), 0, stream>>>(bufX, bufHb, bWih, bWhh, bih, bhh, out, bufHn);

  // ph = silu(h_new @ Wpr1^T + b) -> reuses stoch buffer
  gemm128<<<dim3(64, 8), dim3(256), 0, stream>>>(
      bufHn, 4096, 4096, (const u16*)nullptr, 0, 0,
      bWpr1, 4096, (const u16*)nullptr, 0,
      bpr1, (float*)nullptr, 0, bufSt, 1024, 1);

  // qh = silu([h_new, embed] @ Wpo1^T + b) -> reuses hb buffer
  gemm128<<<dim3(64, 8), dim3(256), 0, stream>>>(
      bufHn, 4096, 4096, bufEm, 1024, 1024,
      bWpo1, 5120, bWpo1 + 4096, 5120,
      bpo1, (float*)nullptr, 0, bufHb, 1024, 1);

  // prior_logits -> out cols [4096,5120)
  gemm128<<<dim3(64, 8), dim3(256), 0, stream>>>(
      bufSt, 1024, 1024, (const u16*)nullptr, 0, 0,
      bWpr2, 1024, (const u16*)nullptr, 0,
      bpr2, out + 4096, OUTLD, (u16*)nullptr, 0, 0);

  // post_logits -> out cols [6144,7168)
  gemm128<<<dim3(64, 8), dim3(256), 0, stream>>>(
      bufHb, 1024, 1024, (const u16*)nullptr, 0, 0,
      bWpo2, 1024, (const u16*)nullptr, 0,
      bpo2, out + 6144, OUTLD, (u16*)nullptr, 0, 0);

  // softmax + unimix -> out cols [5120,6144)
  k_softmax<<<dim3(1024), dim3(256), 0, stream>>>(out);
}

// Round 3
// 775.211 us; speedup vs baseline: 1.1184x; 1.0929x over previous
//
#include <hip/hip_runtime.h>

typedef unsigned short u16;
typedef short bf16x8 __attribute__((ext_vector_type(8)));
typedef float f32x4 __attribute__((ext_vector_type(4)));

#define BSZ 8192
#define OUTLD 7168

__device__ __forceinline__ u16 f2bf(float f) {
  union { float f; unsigned u; } v; v.f = f;
  unsigned r = v.u + 0x7FFFu + ((v.u >> 16) & 1u);
  return (u16)(r >> 16);
}
__device__ __forceinline__ float bf2f(u16 h) {
  union { unsigned u; float f; } v; v.u = ((unsigned)h) << 16;
  return v.f;
}
__device__ __forceinline__ float sigmoidf_(float x) { return 1.0f / (1.0f + __expf(-x)); }

// async global->LDS, 16B per lane; lds dest = wave-uniform base + lane*16
__device__ __forceinline__ void gload16(const u16* g, u16* l) {
  __builtin_amdgcn_global_load_lds(
      (const __attribute__((address_space(1))) void*)g,
      (__attribute__((address_space(3))) void*)l, 16, 0, 0);
}

// ---- is_first dtype detection (bool8 vs int32 vs f32 0/1) ----
__global__ void k_detect(const unsigned* __restrict__ isf, int* __restrict__ flag) {
  __shared__ unsigned red;
  if (threadIdx.x == 0) red = 0u;
  __syncthreads();
  unsigned v = 0;
  for (int i = threadIdx.x; i < 2048; i += 256) v |= isf[i];
  atomicOr(&red, v);
  __syncthreads();
  if (threadIdx.x == 0)
    *flag = (((red & 0xFFFFFF00u) != 0u) && ((red & 0xFEFEFEFEu) == 0u)) ? 1 : 0;
}

__device__ __forceinline__ bool is_first_row(const void* isf, int fl, int b) {
  return fl ? (((const unsigned char*)isf)[b] != 0) : (((const int*)isf)[b] != 0);
}

// ---- f32 -> bf16 convert, optional per-row is_first zeroing ----
__global__ void k_reset_cvt(const float* __restrict__ src, u16* __restrict__ dst,
                            const void* __restrict__ isf, const int* __restrict__ flag,
                            int c4, long n4, int doReset) {
  int fl = flag ? *flag : 0;
  long stride = (long)gridDim.x * blockDim.x;
  for (long i = blockIdx.x * (long)blockDim.x + threadIdx.x; i < n4; i += stride) {
    float4 v = ((const float4*)src)[i];
    if (doReset && is_first_row(isf, fl, (int)(i / c4))) { v.x = v.y = v.z = v.w = 0.f; }
    ushort4 o; o.x = f2bf(v.x); o.y = f2bf(v.y); o.z = f2bf(v.z); o.w = f2bf(v.w);
    ((ushort4*)dst)[i] = o;
  }
}

// ---- action normalize + tiny K=8 encoder -> x[:, 0:1024] (4 h per thread) ----
__global__ void k_ae(const float* __restrict__ act, const float* __restrict__ Wact,
                     const float* __restrict__ bact, u16* __restrict__ x) {
  long stride = (long)gridDim.x * blockDim.x;
  for (long t = blockIdx.x * (long)blockDim.x + threadIdx.x; t < (long)BSZ * 256; t += stride) {
    int b = (int)(t >> 8), h0 = (int)(t & 255) * 4;
    float4 a0 = ((const float4*)act)[b * 2];
    float4 a1 = ((const float4*)act)[b * 2 + 1];
    float mag = fmaxf(
        fmaxf(fmaxf(fabsf(a0.x), fabsf(a0.y)), fmaxf(fabsf(a0.z), fabsf(a0.w))),
        fmaxf(fmaxf(fabsf(a1.x), fabsf(a1.y)), fmaxf(fabsf(a1.z), fabsf(a1.w))));
    float inv = 1.0f / fmaxf(mag, 1.0f);
    ushort4 o;
    u16* op = (u16*)&o;
#pragma unroll
    for (int j = 0; j < 4; ++j) {
      int h = h0 + j;
      float4 w0 = ((const float4*)Wact)[h * 2];
      float4 w1 = ((const float4*)Wact)[h * 2 + 1];
      float dot = a0.x * w0.x + a0.y * w0.y + a0.z * w0.z + a0.w * w0.w
                + a1.x * w1.x + a1.y * w1.y + a1.z * w1.z + a1.w * w1.w;
      op[j] = f2bf(dot * inv + bact[h]);
    }
    *(ushort4*)&x[(long)b * 2048 + h0] = o;
  }
}

// T2 swizzle (both-sides, rule #21): LDS stays linear for global_load_lds;
// global SOURCE slot is pre-permuted (slot ^ (row&7)) and the ds_read applies
// the same XOR. Rows are 128B (one full 32-bank wrap) so unswizzled reads are
// 16-way conflicted; swizzled reads fan each 8-lane stripe across all 8 slots.

// ---- generic 128x128 bf16 MFMA GEMM: C = A@W^T (+A2@W2^T) + bias ----
__global__ __launch_bounds__(256) void gemm128(
    const u16* __restrict__ A1, int lda1, int K1,
    const u16* __restrict__ A2, int lda2, int K2,
    const u16* __restrict__ W1, int ldw1,
    const u16* __restrict__ W2, int ldw2,
    const float* __restrict__ bias,
    float* __restrict__ outF, int ldoF,
    u16* __restrict__ outB, int ldoB,
    int actSilu)
{
  __shared__ __align__(16) u16 lsA[128 * 64];
  __shared__ __align__(16) u16 lsB[128 * 64];
  const int tid = threadIdx.x;
  const int wave = tid >> 6, lane = tid & 63;
  const int m0 = blockIdx.x * 128, n0 = blockIdx.y * 128;
  const int wr = (wave >> 1) * 64, wc = (wave & 1) * 64;
  const int lrow = lane & 15;
  const int lq = lane >> 4;          // k-slot index 0..3
  const int lr7 = lrow & 7;
  // staging: row within 32-row chunk = wave*8 + lane/8; source slot pre-swizzled
  const int grow = wave * 8 + (lane >> 3);
  const int gcol = ((lane & 7) ^ (lane >> 3)) * 8;
  // read offsets (u16) within a row for kk=0,1: slot = (kk*4+lq) ^ lr7
  const int ro0 = ((lq ^ lr7)) * 8;
  const int ro1 = (((4 | lq) ^ lr7)) * 8;

  const f32x4 z4 = {0.f, 0.f, 0.f, 0.f};
  f32x4 acc[4][4];
#pragma unroll
  for (int m = 0; m < 4; ++m)
#pragma unroll
    for (int c = 0; c < 4; ++c) acc[m][c] = z4;

#pragma unroll 1
  for (int phse = 0; phse < 2; ++phse) {
    const u16* A = phse ? A2 : A1;
    const u16* W = phse ? W2 : W1;
    const int lda = phse ? lda2 : lda1;
    const int ldw = phse ? ldw2 : ldw1;
    const int K = phse ? K2 : K1;
#pragma unroll 1
    for (int k0 = 0; k0 < K; k0 += 64) {
      __syncthreads();
#pragma unroll
      for (int i = 0; i < 4; ++i) {
        gload16(&A[(long)(m0 + i * 32 + grow) * lda + k0 + gcol], &lsA[i * 2048 + wave * 512]);
        gload16(&W[(long)(n0 + i * 32 + grow) * ldw + k0 + gcol], &lsB[i * 2048 + wave * 512]);
      }
      __syncthreads();
#pragma unroll
      for (int kk = 0; kk < 2; ++kk) {
        const int ro = kk ? ro1 : ro0;
        bf16x8 af[4], wfr[4];
#pragma unroll
        for (int m = 0; m < 4; ++m)
          af[m] = *(const bf16x8*)&lsA[(wr + m * 16 + lrow) * 64 + ro];
#pragma unroll
        for (int c = 0; c < 4; ++c)
          wfr[c] = *(const bf16x8*)&lsB[(wc + c * 16 + lrow) * 64 + ro];
#pragma unroll
        for (int m = 0; m < 4; ++m)
#pragma unroll
          for (int c = 0; c < 4; ++c)
            acc[m][c] = __builtin_amdgcn_mfma_f32_16x16x32_bf16(af[m], wfr[c], acc[m][c], 0, 0, 0);
      }
    }
  }

#pragma unroll
  for (int c = 0; c < 4; ++c) {
    const int col = n0 + wc + c * 16 + lrow;
    const float bv = bias ? bias[col] : 0.f;
#pragma unroll
    for (int m = 0; m < 4; ++m) {
      const int rowb = m0 + wr + m * 16 + (lane >> 4) * 4;
#pragma unroll
      for (int r = 0; r < 4; ++r) {
        float v = acc[m][c][r] + bv;
        if (actSilu) v = v * sigmoidf_(v);
        if (outF) outF[(long)(rowb + r) * ldoF + col] = v;
        if (outB) outB[(long)(rowb + r) * ldoB + col] = f2bf(v);
      }
    }
  }
}

// ---- block-diagonal GRU: 3 gates for same 64 cols in one block, fused epilogue ----
__global__ __launch_bounds__(256) void gru128(
    const u16* __restrict__ xbuf, const u16* __restrict__ hbuf,
    const u16* __restrict__ Wih, const u16* __restrict__ Whh,
    const float* __restrict__ bih, const float* __restrict__ bhh,
    float* __restrict__ outF, u16* __restrict__ hnew)
{
  __shared__ __align__(16) u16 lsA[128 * 64];
  __shared__ __align__(16) u16 lsW[3 * 64 * 64];
  const int tid = threadIdx.x;
  const int wave = tid >> 6, lane = tid & 63;
  const int m0 = blockIdx.x * 128;
  const int blk = blockIdx.y >> 3;
  const int s0 = (blockIdx.y & 7) * 64;
  const int lrow = lane & 15;
  const int lq = lane >> 4;
  const int lr7 = lrow & 7;
  const int grow = wave * 8 + (lane >> 3);
  const int gcol = ((lane & 7) ^ (lane >> 3)) * 8;   // pre-swizzled source slot
  const int ro0 = ((lq ^ lr7)) * 8;
  const int ro1 = (((4 | lq) ^ lr7)) * 8;

  const f32x4 z4 = {0.f, 0.f, 0.f, 0.f};
  f32x4 acc[3][2][4];
#pragma unroll
  for (int g = 0; g < 3; ++g)
#pragma unroll
    for (int m = 0; m < 2; ++m)
#pragma unroll
      for (int c = 0; c < 4; ++c) acc[g][m][c] = z4;

#pragma unroll 1
  for (int phse = 0; phse < 2; ++phse) {
    const u16* A = phse ? (hbuf + blk * 512) : (xbuf + blk * 256);
    const u16* W = phse ? (Whh + (long)blk * 1536 * 512) : (Wih + (long)blk * 1536 * 256);
    const int lda = phse ? 4096 : 2048;
    const int ldw = phse ? 512 : 256;
    const int K = phse ? 512 : 256;
#pragma unroll 1
    for (int k0 = 0; k0 < K; k0 += 64) {
      __syncthreads();
#pragma unroll
      for (int i = 0; i < 4; ++i)
        gload16(&A[(long)(m0 + i * 32 + grow) * lda + k0 + gcol], &lsA[i * 2048 + wave * 512]);
      // W tile: 3 gates x 64 rows x 64 cols = 24 chunks of 512 u16
#pragma unroll
      for (int j = 0; j < 6; ++j) {
        const int idx = j * 4 + wave;           // chunk 0..23
        const int off = idx * 512;
        const int g = off >> 12;                // gate
        const int r0 = (off & 4095) >> 6;       // starting row (multiple of 8)
        gload16(&W[(long)(g * 512 + s0 + r0 + (lane >> 3)) * ldw + k0 + gcol], &lsW[off]);
      }
      __syncthreads();
#pragma unroll
      for (int kk = 0; kk < 2; ++kk) {
        const int ro = kk ? ro1 : ro0;
        bf16x8 af[2], wfr[3][4];
#pragma unroll
        for (int m = 0; m < 2; ++m)
          af[m] = *(const bf16x8*)&lsA[(wave * 32 + m * 16 + lrow) * 64 + ro];
#pragma unroll
        for (int g = 0; g < 3; ++g)
#pragma unroll
          for (int c = 0; c < 4; ++c)
            wfr[g][c] = *(const bf16x8*)&lsW[g * 4096 + (c * 16 + lrow) * 64 + ro];
#pragma unroll
        for (int g = 0; g < 3; ++g)
#pragma unroll
          for (int m = 0; m < 2; ++m)
#pragma unroll
            for (int c = 0; c < 4; ++c)
              acc[g][m][c] = __builtin_amdgcn_mfma_f32_16x16x32_bf16(af[m], wfr[g][c], acc[g][m][c], 0, 0, 0);
      }
    }
  }

#pragma unroll
  for (int c = 0; c < 4; ++c) {
    const int s = s0 + c * 16 + lrow;
    const int bb = blk * 1536 + s;
    const float br = bih[bb] + bhh[bb];
    const float bu = bih[bb + 512] + bhh[bb + 512];
    const float bc = bih[bb + 1024] + bhh[bb + 1024];
    const int hcol = blk * 512 + s;
#pragma unroll
    for (int m = 0; m < 2; ++m) {
      const int rowb = m0 + wave * 32 + m * 16 + (lane >> 4) * 4;
#pragma unroll
      for (int r = 0; r < 4; ++r) {
        const int row = rowb + r;
        const float gr = acc[0][m][c][r] + br;
        const float gu = acc[1][m][c][r] + bu;
        const float gc = acc[2][m][c][r] + bc;
        const float rr = sigmoidf_(gr);
        const float uu = sigmoidf_(gu);
        const float cand = tanhf(rr * gc);
        const float h = bf2f(hbuf[(long)row * 4096 + hcol]);
        const float hn = (1.f - uu) * h + uu * cand;
        outF[(long)row * OUTLD + hcol] = hn;
        hnew[(long)row * 4096 + hcol] = f2bf(hn);
      }
    }
  }
}

// ---- softmax over C=32 groups + unimix ----
__global__ void k_softmax(float* __restrict__ out) {
  int t = blockIdx.x * blockDim.x + threadIdx.x;  // b*32+g
  if (t >= BSZ * 32) return;
  int b = t >> 5, g = t & 31;
  const float* src = out + (long)b * OUTLD + 4096 + g * 32;
  float* dst = out + (long)b * OUTLD + 5120 + g * 32;
  float v[32];
#pragma unroll
  for (int i = 0; i < 8; ++i) {
    float4 q = ((const float4*)src)[i];
    v[4 * i] = q.x; v[4 * i + 1] = q.y; v[4 * i + 2] = q.z; v[4 * i + 3] = q.w;
  }
  float m = v[0];
#pragma unroll
  for (int i = 1; i < 32; ++i) m = fmaxf(m, v[i]);
  float ssum = 0.f;
#pragma unroll
  for (int i = 0; i < 32; ++i) { v[i] = __expf(v[i] - m); ssum += v[i]; }
  float inv = 0.99f / ssum;
#pragma unroll
  for (int i = 0; i < 8; ++i) {
    float4 q;
    q.x = v[4 * i] * inv + 3.125e-4f;
    q.y = v[4 * i + 1] * inv + 3.125e-4f;
    q.z = v[4 * i + 2] * inv + 3.125e-4f;
    q.w = v[4 * i + 3] * inv + 3.125e-4f;
    ((float4*)dst)[i] = q;
  }
}

extern "C" void kernel_launch(void* const* d_in, const int* in_sizes, int n_in,
                              void* d_out, int out_size, void* d_ws, size_t ws_size,
                              hipStream_t stream) {
  const float* det   = (const float*)d_in[0];
  const float* stoch = (const float*)d_in[1];
  const float* pact  = (const float*)d_in[2];
  const float* embed = (const float*)d_in[3];
  const void*  isf   = d_in[4];
  const float* Wact  = (const float*)d_in[5];
  const float* bact  = (const float*)d_in[6];
  const float* Wst   = (const float*)d_in[7];
  const float* bst   = (const float*)d_in[8];
  const float* Wih   = (const float*)d_in[9];
  const float* bih   = (const float*)d_in[10];
  const float* Whh   = (const float*)d_in[11];
  const float* bhh   = (const float*)d_in[12];
  const float* Wpr1  = (const float*)d_in[13];
  const float* bpr1  = (const float*)d_in[14];
  const float* Wpr2  = (const float*)d_in[15];
  const float* bpr2  = (const float*)d_in[16];
  const float* Wpo1  = (const float*)d_in[17];
  const float* bpo1  = (const float*)d_in[18];
  const float* Wpo2  = (const float*)d_in[19];
  const float* bpo2  = (const float*)d_in[20];
  float* out = (float*)d_out;

  // ws layout (u16 elements after a 256B header). Total ~235 MB.
  int* flag = (int*)d_ws;
  u16* wsu  = (u16*)((char*)d_ws + 256);
  u16* bWst  = wsu;                   // 1,048,576
  u16* bWih  = wsu + 1048576UL;       // 3,145,728
  u16* bWhh  = wsu + 4194304UL;       // 6,291,456
  u16* bWpr1 = wsu + 10485760UL;      // 4,194,304
  u16* bWpr2 = wsu + 14680064UL;      // 1,048,576
  u16* bWpo1 = wsu + 15728640UL;      // 5,242,880
  u16* bWpo2 = wsu + 20971520UL;      // 1,048,576
  u16* bufX  = wsu + 22020096UL;      // 16,777,216  [B,2048]
  u16* bufSt = wsu + 38797312UL;      // 8,388,608   stoch -> later ph
  u16* bufHb = wsu + 47185920UL;      // 33,554,432  hb -> later qh
  u16* bufHn = wsu + 80740352UL;      // 33,554,432  h_new bf16
  u16* bufEm = wsu + 114294784UL;     // 8,388,608   embed bf16

  k_detect<<<dim3(1), dim3(256), 0, stream>>>((const unsigned*)isf, flag);

  // weight conversions f32 -> bf16
  struct CV { const float* s; u16* d; long n; };
  CV cvs[7] = {
    {Wst,  bWst,  1048576L}, {Wih,  bWih,  3145728L}, {Whh,  bWhh,  6291456L},
    {Wpr1, bWpr1, 4194304L}, {Wpr2, bWpr2, 1048576L}, {Wpo1, bWpo1, 5242880L},
    {Wpo2, bWpo2, 1048576L}
  };
  for (int i = 0; i < 7; ++i) {
    long n4 = cvs[i].n / 4;
    int blocks = (int)((n4 + 255) / 256); if (blocks > 4096) blocks = 4096;
    k_reset_cvt<<<dim3(blocks), dim3(256), 0, stream>>>(
        cvs[i].s, cvs[i].d, (const void*)nullptr, (const int*)nullptr, 1, n4, 0);
  }

  // input prep
  k_ae<<<dim3(2048), dim3(256), 0, stream>>>(pact, Wact, bact, bufX);
  k_reset_cvt<<<dim3(4096), dim3(256), 0, stream>>>(stoch, bufSt, isf, flag, 256, 2097152L, 1);
  k_reset_cvt<<<dim3(4096), dim3(256), 0, stream>>>(det, bufHb, isf, flag, 1024, 8388608L, 1);
  k_reset_cvt<<<dim3(4096), dim3(256), 0, stream>>>(embed, bufEm, (const void*)nullptr,
                                                    (const int*)nullptr, 256, 2097152L, 0);

  // se = stoch @ Wst^T + b  -> x[:, 1024:2048]
  gemm128<<<dim3(64, 8), dim3(256), 0, stream>>>(
      bufSt, 1024, 1024, (const u16*)nullptr, 0, 0,
      bWst, 1024, (const u16*)nullptr, 0,
      bst, (float*)nullptr, 0, bufX + 1024, 2048, 0);

  // GRU -> h_new (f32 to out cols [0,4096), bf16 to ws)
  gru128<<<dim3(64, 64), dim3(256), 0, stream>>>(bufX, bufHb, bWih, bWhh, bih, bhh, out, bufHn);

  // ph = silu(h_new @ Wpr1^T + b) -> reuses stoch buffer
  gemm128<<<dim3(64, 8), dim3(256), 0, stream>>>(
      bufHn, 4096, 4096, (const u16*)nullptr, 0, 0,
      bWpr1, 4096, (const u16*)nullptr, 0,
      bpr1, (float*)nullptr, 0, bufSt, 1024, 1);

  // qh = silu([h_new, embed] @ Wpo1^T + b) -> reuses hb buffer
  gemm128<<<dim3(64, 8), dim3(256), 0, stream>>>(
      bufHn, 4096, 4096, bufEm, 1024, 1024,
      bWpo1, 5120, bWpo1 + 4096, 5120,
      bpo1, (float*)nullptr, 0, bufHb, 1024, 1);

  // prior_logits -> out cols [4096,5120)
  gemm128<<<dim3(64, 8), dim3(256), 0, stream>>>(
      bufSt, 1024, 1024, (const u16*)nullptr, 0, 0,
      bWpr2, 1024, (const u16*)nullptr, 0,
      bpr2, out + 4096, OUTLD, (u16*)nullptr, 0, 0);

  // post_logits -> out cols [6144,7168)
  gemm128<<<dim3(64, 8), dim3(256), 0, stream>>>(
      bufHb, 1024, 1024, (const u16*)nullptr, 0, 0,
      bWpo2, 1024, (const u16*)nullptr, 0,
      bpo2, out + 6144, OUTLD, (u16*)nullptr, 0, 0);

  // softmax + unimix -> out cols [5120,6144)
  k_softmax<<<dim3(1024), dim3(256), 0, stream>>>(out);
}